// Round 2
// baseline (986.610 us; speedup 1.0000x reference)
//
#include <hip/hip_runtime.h>

#define NN 100000
#define NE 1600000
#define FD 64
#define HD 64
#define NCLS 16

// ---- degree count (atomic) ----
__global__ void k_deg(const int* __restrict__ row, int* __restrict__ deg) {
    int e = blockIdx.x * 256 + threadIdx.x;
    if (e < NE) atomicAdd(&deg[row[e]], 1);
}

__global__ void k_dinv(const int* __restrict__ deg, float* __restrict__ dinv) {
    int n = blockIdx.x * 256 + threadIdx.x;
    if (n < NN) {
        int d = deg[n];
        dinv[n] = d > 0 ? rsqrtf((float)d) : 0.0f;
    }
}

// ---- 3-kernel exclusive scan over deg -> row_ptr ----
__global__ void k_scan1(const int* __restrict__ deg, int* __restrict__ part, int* __restrict__ bsum) {
    __shared__ int s[256];
    int t = threadIdx.x, g = blockIdx.x * 256 + t;
    int d = (g < NN) ? deg[g] : 0;
    s[t] = d; __syncthreads();
    for (int off = 1; off < 256; off <<= 1) {
        int v = (t >= off) ? s[t - off] : 0;
        __syncthreads();
        s[t] += v;
        __syncthreads();
    }
    if (g < NN) part[g] = s[t] - d;          // exclusive
    if (t == 255) bsum[blockIdx.x] = s[t];   // block total
}

__global__ void k_scan2(int* __restrict__ bsum, int nb) {
    __shared__ int s[512];
    int t = threadIdx.x;
    int d = (t < nb) ? bsum[t] : 0;
    s[t] = d; __syncthreads();
    for (int off = 1; off < 512; off <<= 1) {
        int v = (t >= off) ? s[t - off] : 0;
        __syncthreads();
        s[t] += v;
        __syncthreads();
    }
    if (t < nb) bsum[t] = s[t] - d;          // exclusive over block sums
}

__global__ void k_scan3(const int* __restrict__ deg, const int* __restrict__ bsum,
                        int* __restrict__ row_ptr, int* __restrict__ cursor) {
    int g = blockIdx.x * 256 + threadIdx.x;
    if (g < NN) {
        int v = row_ptr[g] + bsum[g >> 8];
        row_ptr[g] = v;
        cursor[g] = v;
        if (g == NN - 1) row_ptr[NN] = v + deg[g];
    }
}

// ---- scatter edges into CSR (order within a row nondeterministic; fp-noise only) ----
__global__ void k_scatter(const int* __restrict__ row, const int* __restrict__ col,
                          int* __restrict__ cursor, int* __restrict__ col_sorted) {
    int e = blockIdx.x * 256 + threadIdx.x;
    if (e < NE) {
        int r = row[e];
        int p = atomicAdd(&cursor[r], 1);
        col_sorted[p] = col[e];
    }
}

// ---- SpMM: out[n][f] = sum_{c in adj(n)} (-dinv[n]*dinv[c]) * in[c][f]
//      if has_sub: out = 2*acc - sub   (Chebyshev recurrence) ----
__global__ __launch_bounds__(256) void k_spmm(const float* __restrict__ in, const float* __restrict__ sub,
                                              float* __restrict__ out, const int* __restrict__ row_ptr,
                                              const int* __restrict__ cs, const float* __restrict__ dinv,
                                              int has_sub) {
    int n = blockIdx.x * 4 + (threadIdx.x >> 6);
    int lane = threadIdx.x & 63;
    if (n >= NN) return;
    int s = row_ptr[n], e = row_ptr[n + 1];
    float dn = dinv[n];
    float acc = 0.0f;
    for (int i = s; i < e; ++i) {
        int c = cs[i];
        acc += (-dn * dinv[c]) * in[c * 64 + lane];
    }
    float r = has_sub ? (2.0f * acc - sub[n * 64 + lane]) : acc;
    out[n * 64 + lane] = r;
}

// ---- dense layer 1: h = relu(x@W[0] + t1@W[1] + t2@W[2] + b), 192x64 per node ----
__global__ __launch_bounds__(256) void k_dense1(const float* __restrict__ x, const float* __restrict__ t1,
                                                const float* __restrict__ t2, const float* __restrict__ W,
                                                const float* __restrict__ b, float* __restrict__ h) {
    __shared__ float Ws[3 * 64 * 64];
    for (int i = threadIdx.x; i < 3 * 64 * 64; i += 256) Ws[i] = W[i];
    __syncthreads();
    int lane = threadIdx.x & 63;
    float bl = b[lane];
    for (int n = blockIdx.x * 4 + (threadIdx.x >> 6); n < NN; n += gridDim.x * 4) {
        float acc = bl;
        const float* tp = x + (size_t)n * 64;
        #pragma unroll
        for (int i = 0; i < 64; ++i) acc += tp[i] * Ws[i * 64 + lane];
        tp = t1 + (size_t)n * 64;
        #pragma unroll
        for (int i = 0; i < 64; ++i) acc += tp[i] * Ws[4096 + i * 64 + lane];
        tp = t2 + (size_t)n * 64;
        #pragma unroll
        for (int i = 0; i < 64; ++i) acc += tp[i] * Ws[8192 + i * 64 + lane];
        h[(size_t)n * 64 + lane] = fmaxf(acc, 0.0f);
    }
}

// ---- dense layer 2 + log_softmax: 16 lanes per node ----
__global__ __launch_bounds__(256) void k_dense2(const float* __restrict__ h, const float* __restrict__ u1,
                                                const float* __restrict__ u2, const float* __restrict__ W,
                                                const float* __restrict__ b, float* __restrict__ out) {
    __shared__ float Ws[3 * 64 * 16];
    for (int i = threadIdx.x; i < 3 * 64 * 16; i += 256) Ws[i] = W[i];
    __syncthreads();
    int slot = threadIdx.x >> 4;   // 16 nodes per block
    int c = threadIdx.x & 15;
    float bc = b[c];
    for (int n = blockIdx.x * 16 + slot; n < NN; n += gridDim.x * 16) {
        float acc = bc;
        const float* tp = h + (size_t)n * 64;
        #pragma unroll
        for (int i = 0; i < 64; ++i) acc += tp[i] * Ws[i * 16 + c];
        tp = u1 + (size_t)n * 64;
        #pragma unroll
        for (int i = 0; i < 64; ++i) acc += tp[i] * Ws[1024 + i * 16 + c];
        tp = u2 + (size_t)n * 64;
        #pragma unroll
        for (int i = 0; i < 64; ++i) acc += tp[i] * Ws[2048 + i * 16 + c];
        // log_softmax across the 16 lanes of this node
        float m = acc;
        for (int off = 1; off < 16; off <<= 1) m = fmaxf(m, __shfl_xor(m, off, 16));
        float ex = expf(acc - m);
        float ssum = ex;
        for (int off = 1; off < 16; off <<= 1) ssum += __shfl_xor(ssum, off, 16);
        out[(size_t)n * 16 + c] = acc - m - logf(ssum);
    }
}

extern "C" void kernel_launch(void* const* d_in, const int* in_sizes, int n_in,
                              void* d_out, int out_size, void* d_ws, size_t ws_size,
                              hipStream_t stream) {
    const float* x  = (const float*)d_in[0];
    const int*   ei = (const int*)d_in[1];
    const int*   row = ei;
    const int*   col = ei + NE;
    const float* W1 = (const float*)d_in[2];
    const float* b1 = (const float*)d_in[3];
    const float* W2 = (const float*)d_in[4];
    const float* b2 = (const float*)d_in[5];
    float* out = (float*)d_out;

    char* base = (char*)d_ws;
    size_t off = 0;
    auto alloc = [&](size_t bytes) -> char* {
        char* r = base + off;
        off = (off + bytes + 255) & ~(size_t)255;
        return r;
    };
    int*   deg        = (int*)alloc((size_t)NN * 4);
    float* dinv       = (float*)alloc((size_t)NN * 4);
    int*   row_ptr    = (int*)alloc((size_t)(NN + 1) * 4);
    int*   cursor     = (int*)alloc((size_t)NN * 4);
    int*   bsum       = (int*)alloc(512 * 4);
    int*   col_sorted = (int*)alloc((size_t)NE * 4);
    float* T1         = (float*)alloc((size_t)NN * 64 * 4);
    float* T2         = (float*)alloc((size_t)NN * 64 * 4);
    float* H          = (float*)alloc((size_t)NN * 64 * 4);

    hipMemsetAsync(deg, 0, (size_t)NN * 4, stream);

    int nbN = (NN + 255) / 256;   // 391
    int nbE = (NE + 255) / 256;   // 6250
    k_deg<<<nbE, 256, 0, stream>>>(row, deg);
    k_dinv<<<nbN, 256, 0, stream>>>(deg, dinv);
    k_scan1<<<nbN, 256, 0, stream>>>(deg, row_ptr, bsum);
    k_scan2<<<1, 512, 0, stream>>>(bsum, nbN);
    k_scan3<<<nbN, 256, 0, stream>>>(deg, bsum, row_ptr, cursor);
    k_scatter<<<nbE, 256, 0, stream>>>(row, col, cursor, col_sorted);

    int nbS = (NN + 3) / 4;       // 25000 blocks, 4 waves each, wave per node
    // layer 1
    k_spmm<<<nbS, 256, 0, stream>>>(x, nullptr, T1, row_ptr, col_sorted, dinv, 0);
    k_spmm<<<nbS, 256, 0, stream>>>(T1, x, T2, row_ptr, col_sorted, dinv, 1);
    k_dense1<<<2048, 256, 0, stream>>>(x, T1, T2, W1, b1, H);
    // layer 2 (reuse T1/T2)
    k_spmm<<<nbS, 256, 0, stream>>>(H, nullptr, T1, row_ptr, col_sorted, dinv, 0);
    k_spmm<<<nbS, 256, 0, stream>>>(T1, H, T2, row_ptr, col_sorted, dinv, 1);
    k_dense2<<<2048, 256, 0, stream>>>(H, T1, T2, W2, b2, out);
}

// Round 5
// 657.352 us; speedup vs baseline: 1.5009x; 1.5009x over previous
//
#include <hip/hip_runtime.h>

#define NN 100000
#define NE 1600000

// ---- degree count (atomic) ----
__global__ void k_deg(const int* __restrict__ row, int* __restrict__ deg) {
    int e = blockIdx.x * 256 + threadIdx.x;
    if (e < NE) atomicAdd(&deg[row[e]], 1);
}

__global__ void k_dinv(const int* __restrict__ deg, float* __restrict__ dinv) {
    int n = blockIdx.x * 256 + threadIdx.x;
    if (n < NN) {
        int d = deg[n];
        dinv[n] = d > 0 ? rsqrtf((float)d) : 0.0f;
    }
}

// ---- xs = x * dinv[node], float4 per thread (16 threads/node) ----
__global__ void k_scale(const float* __restrict__ x, const float* __restrict__ dinv,
                        float* __restrict__ xs) {
    int t = blockIdx.x * 256 + threadIdx.x;
    if (t < NN * 16) {
        float d = dinv[t >> 4];
        float4 v = ((const float4*)x)[t];
        v.x *= d; v.y *= d; v.z *= d; v.w *= d;
        ((float4*)xs)[t] = v;
    }
}

// ---- 3-kernel exclusive scan over deg -> row_ptr ----
__global__ void k_scan1(const int* __restrict__ deg, int* __restrict__ part, int* __restrict__ bsum) {
    __shared__ int s[256];
    int t = threadIdx.x, g = blockIdx.x * 256 + t;
    int d = (g < NN) ? deg[g] : 0;
    s[t] = d; __syncthreads();
    for (int off = 1; off < 256; off <<= 1) {
        int v = (t >= off) ? s[t - off] : 0;
        __syncthreads();
        s[t] += v;
        __syncthreads();
    }
    if (g < NN) part[g] = s[t] - d;
    if (t == 255) bsum[blockIdx.x] = s[t];
}

__global__ void k_scan2(int* __restrict__ bsum, int nb) {
    __shared__ int s[512];
    int t = threadIdx.x;
    int d = (t < nb) ? bsum[t] : 0;
    s[t] = d; __syncthreads();
    for (int off = 1; off < 512; off <<= 1) {
        int v = (t >= off) ? s[t - off] : 0;
        __syncthreads();
        s[t] += v;
        __syncthreads();
    }
    if (t < nb) bsum[t] = s[t] - d;
}

__global__ void k_scan3(const int* __restrict__ deg, const int* __restrict__ bsum,
                        int* __restrict__ row_ptr, int* __restrict__ cursor) {
    int g = blockIdx.x * 256 + threadIdx.x;
    if (g < NN) {
        int v = row_ptr[g] + bsum[g >> 8];
        row_ptr[g] = v;
        cursor[g] = v;
        if (g == NN - 1) row_ptr[NN] = v + deg[g];
    }
}

__global__ void k_scatter(const int* __restrict__ row, const int* __restrict__ col,
                          int* __restrict__ cursor, int* __restrict__ col_sorted) {
    int e = blockIdx.x * 256 + threadIdx.x;
    if (e < NE) {
        int r = row[e];
        int p = atomicAdd(&cursor[r], 1);
        col_sorted[p] = col[e];
    }
}

// ---- SpMM on pre-scaled input: out[n] = -dinv[n] * sum_{c} ins[c]
//      has_sub: out = 2*out - sub; has_outs: outs = dinv[n]*out ----
__global__ __launch_bounds__(256) void k_spmm(const float* __restrict__ ins, const float* __restrict__ sub,
                                              float* __restrict__ out, float* __restrict__ outs,
                                              const int* __restrict__ row_ptr, const int* __restrict__ cs,
                                              const float* __restrict__ dinv,
                                              int has_sub, int has_outs) {
    int n = blockIdx.x * 4 + (threadIdx.x >> 6);
    if (n >= NN) return;
    int nu = __builtin_amdgcn_readfirstlane(n);
    int lane = threadIdx.x & 63;
    int half = lane >> 5;
    int m = lane & 31;
    int s = row_ptr[nu], e = row_ptr[nu + 1];
    float ax0 = 0.f, ay0 = 0.f, ax1 = 0.f, ay1 = 0.f;
    int i = s;
    // 4 edges per iteration: half-wave split (2) x unroll (2) -> 4 gathers in flight
    for (; i + 3 < e; i += 4) {
        int c0 = cs[i + half];
        int c1 = cs[i + 2 + half];
        float2 v0 = ((const float2*)(ins + (size_t)c0 * 64))[m];
        float2 v1 = ((const float2*)(ins + (size_t)c1 * 64))[m];
        ax0 += v0.x; ay0 += v0.y;
        ax1 += v1.x; ay1 += v1.y;
    }
    for (; i + 1 < e; i += 2) {
        int c = cs[i + half];
        float2 v = ((const float2*)(ins + (size_t)c * 64))[m];
        ax0 += v.x; ay0 += v.y;
    }
    if (i < e && half == 0) {
        int c = cs[i];
        float2 v = ((const float2*)(ins + (size_t)c * 64))[m];
        ax0 += v.x; ay0 += v.y;
    }
    float ax = ax0 + ax1, ay = ay0 + ay1;
    ax += __shfl_xor(ax, 32);
    ay += __shfl_xor(ay, 32);
    if (half == 0) {
        float dn = dinv[nu];
        float rx = -dn * ax, ry = -dn * ay;
        if (has_sub) {
            float2 sv = ((const float2*)(sub + (size_t)nu * 64))[m];
            rx = 2.f * rx - sv.x;
            ry = 2.f * ry - sv.y;
        }
        float2 r; r.x = rx; r.y = ry;
        ((float2*)(out + (size_t)nu * 64))[m] = r;
        if (has_outs) {
            float2 rs; rs.x = dn * rx; rs.y = dn * ry;
            ((float2*)(outs + (size_t)nu * 64))[m] = rs;
        }
    }
}

// ---- dense layer 1: h = relu(x@W0 + t1@W1 + t2@W2 + b); hs = dinv*h
//      wave = 8 nodes; 1 LDS read per 8 FMA; uniform scalar row loads ----
__global__ __launch_bounds__(256) void k_dense1(const float* __restrict__ x, const float* __restrict__ t1,
                                                const float* __restrict__ t2, const float* __restrict__ W,
                                                const float* __restrict__ b, const float* __restrict__ dinv,
                                                float* __restrict__ h, float* __restrict__ hs) {
    __shared__ float Ws[3 * 64 * 64];
    for (int i = threadIdx.x; i < 3 * 64 * 64; i += 256) Ws[i] = W[i];
    __syncthreads();
    int lane = threadIdx.x & 63;
    int n0 = __builtin_amdgcn_readfirstlane((blockIdx.x * 4 + (threadIdx.x >> 6)) * 8);
    if (n0 >= NN) return;
    float bl = b[lane];
    float acc[8];
    #pragma unroll
    for (int j = 0; j < 8; ++j) acc[j] = bl;
    const float* arrs[3] = {x, t1, t2};
    #pragma unroll
    for (int s3 = 0; s3 < 3; ++s3) {
        const float* A = arrs[s3] + (size_t)n0 * 64;
        const float* Wp = Ws + s3 * 4096;
        #pragma unroll 4
        for (int i = 0; i < 64; ++i) {
            float w = Wp[i * 64 + lane];
            #pragma unroll
            for (int j = 0; j < 8; ++j) acc[j] += A[j * 64 + i] * w;
        }
    }
    #pragma unroll
    for (int j = 0; j < 8; ++j) {
        float v = fmaxf(acc[j], 0.f);
        h[(size_t)(n0 + j) * 64 + lane] = v;
        hs[(size_t)(n0 + j) * 64 + lane] = v * dinv[n0 + j];
    }
}

// ---- dense layer 2 + log_softmax: 16 lanes per node ----
__global__ __launch_bounds__(256) void k_dense2(const float* __restrict__ h, const float* __restrict__ u1,
                                                const float* __restrict__ u2, const float* __restrict__ W,
                                                const float* __restrict__ b, float* __restrict__ out) {
    __shared__ float Ws[3 * 64 * 16];
    for (int i = threadIdx.x; i < 3 * 64 * 16; i += 256) Ws[i] = W[i];
    __syncthreads();
    int slot = threadIdx.x >> 4;
    int c = threadIdx.x & 15;
    float bc = b[c];
    for (int n = blockIdx.x * 16 + slot; n < NN; n += gridDim.x * 16) {
        float acc = bc;
        const float* tp = h + (size_t)n * 64;
        #pragma unroll
        for (int i = 0; i < 64; ++i) acc += tp[i] * Ws[i * 16 + c];
        tp = u1 + (size_t)n * 64;
        #pragma unroll
        for (int i = 0; i < 64; ++i) acc += tp[i] * Ws[1024 + i * 16 + c];
        tp = u2 + (size_t)n * 64;
        #pragma unroll
        for (int i = 0; i < 64; ++i) acc += tp[i] * Ws[2048 + i * 16 + c];
        float m = acc;
        for (int off = 1; off < 16; off <<= 1) m = fmaxf(m, __shfl_xor(m, off, 16));
        float ex = expf(acc - m);
        float ssum = ex;
        for (int off = 1; off < 16; off <<= 1) ssum += __shfl_xor(ssum, off, 16);
        out[(size_t)n * 16 + c] = acc - m - logf(ssum);
    }
}

extern "C" void kernel_launch(void* const* d_in, const int* in_sizes, int n_in,
                              void* d_out, int out_size, void* d_ws, size_t ws_size,
                              hipStream_t stream) {
    const float* x  = (const float*)d_in[0];
    const int*   ei = (const int*)d_in[1];
    const int*   row = ei;
    const int*   col = ei + NE;
    const float* W1 = (const float*)d_in[2];
    const float* b1 = (const float*)d_in[3];
    const float* W2 = (const float*)d_in[4];
    const float* b2 = (const float*)d_in[5];
    float* out = (float*)d_out;

    char* base = (char*)d_ws;
    size_t off = 0;
    auto alloc = [&](size_t bytes) -> char* {
        char* r = base + off;
        off = (off + bytes + 255) & ~(size_t)255;
        return r;
    };
    int*   deg        = (int*)alloc((size_t)NN * 4);
    float* dinv       = (float*)alloc((size_t)NN * 4);
    int*   row_ptr    = (int*)alloc((size_t)(NN + 1) * 4);
    int*   cursor     = (int*)alloc((size_t)NN * 4);
    int*   bsum       = (int*)alloc(512 * 4);
    int*   col_sorted = (int*)alloc((size_t)NE * 4);
    float* XS         = (float*)alloc((size_t)NN * 64 * 4);  // also reused as U2
    float* T1         = (float*)alloc((size_t)NN * 64 * 4);  // also U1
    float* T1s        = (float*)alloc((size_t)NN * 64 * 4);  // also U1s
    float* T2         = (float*)alloc((size_t)NN * 64 * 4);
    float* H          = (float*)alloc((size_t)NN * 64 * 4);
    float* Hs         = (float*)alloc((size_t)NN * 64 * 4);

    hipMemsetAsync(deg, 0, (size_t)NN * 4, stream);

    int nbN = (NN + 255) / 256;
    int nbE = (NE + 255) / 256;
    k_deg<<<nbE, 256, 0, stream>>>(row, deg);
    k_dinv<<<nbN, 256, 0, stream>>>(deg, dinv);
    k_scale<<<(NN * 16 + 255) / 256, 256, 0, stream>>>(x, dinv, XS);
    k_scan1<<<nbN, 256, 0, stream>>>(deg, row_ptr, bsum);
    k_scan2<<<1, 512, 0, stream>>>(bsum, nbN);
    k_scan3<<<nbN, 256, 0, stream>>>(deg, bsum, row_ptr, cursor);
    k_scatter<<<nbE, 256, 0, stream>>>(row, col, cursor, col_sorted);

    int nbS = (NN + 3) / 4;   // wave per node
    // layer 1
    k_spmm<<<nbS, 256, 0, stream>>>(XS, nullptr, T1, T1s, row_ptr, col_sorted, dinv, 0, 1);
    k_spmm<<<nbS, 256, 0, stream>>>(T1s, x, T2, nullptr, row_ptr, col_sorted, dinv, 1, 0);
    k_dense1<<<3125, 256, 0, stream>>>(x, T1, T2, W1, b1, dinv, H, Hs);
    // layer 2 (XS dead -> U2; T1 -> U1; T1s -> U1s)
    float* U1 = T1; float* U1s = T1s; float* U2 = XS;
    k_spmm<<<nbS, 256, 0, stream>>>(Hs, nullptr, U1, U1s, row_ptr, col_sorted, dinv, 0, 1);
    k_spmm<<<nbS, 256, 0, stream>>>(U1s, H, U2, nullptr, row_ptr, col_sorted, dinv, 1, 0);
    k_dense2<<<2048, 256, 0, stream>>>(H, U1, U2, W2, b2, out);
}

// Round 6
// 528.579 us; speedup vs baseline: 1.8665x; 1.2436x over previous
//
#include <hip/hip_runtime.h>

#define NN 100000
#define NE 1600000

// ---- degree count: 4 edges/thread for atomic MLP ----
__global__ void k_deg(const int* __restrict__ row, int* __restrict__ deg) {
    int base = blockIdx.x * 1024 + threadIdx.x;
    #pragma unroll
    for (int j = 0; j < 4; ++j) {
        int e = base + j * 256;
        if (e < NE) atomicAdd(&deg[row[e]], 1);
    }
}

__global__ void k_dinv(const int* __restrict__ deg, float* __restrict__ dinv) {
    int n = blockIdx.x * 256 + threadIdx.x;
    if (n < NN) {
        int d = deg[n];
        dinv[n] = d > 0 ? rsqrtf((float)d) : 0.0f;
    }
}

// ---- xs = x * dinv[node], float4 per thread ----
__global__ void k_scale(const float* __restrict__ x, const float* __restrict__ dinv,
                        float* __restrict__ xs) {
    int t = blockIdx.x * 256 + threadIdx.x;
    if (t < NN * 16) {
        float d = dinv[t >> 4];
        float4 v = ((const float4*)x)[t];
        v.x *= d; v.y *= d; v.z *= d; v.w *= d;
        ((float4*)xs)[t] = v;
    }
}

// ---- 3-kernel exclusive scan over deg -> row_ptr ----
__global__ void k_scan1(const int* __restrict__ deg, int* __restrict__ part, int* __restrict__ bsum) {
    __shared__ int s[256];
    int t = threadIdx.x, g = blockIdx.x * 256 + t;
    int d = (g < NN) ? deg[g] : 0;
    s[t] = d; __syncthreads();
    for (int off = 1; off < 256; off <<= 1) {
        int v = (t >= off) ? s[t - off] : 0;
        __syncthreads();
        s[t] += v;
        __syncthreads();
    }
    if (g < NN) part[g] = s[t] - d;
    if (t == 255) bsum[blockIdx.x] = s[t];
}

__global__ void k_scan2(int* __restrict__ bsum, int nb) {
    __shared__ int s[512];
    int t = threadIdx.x;
    int d = (t < nb) ? bsum[t] : 0;
    s[t] = d; __syncthreads();
    for (int off = 1; off < 512; off <<= 1) {
        int v = (t >= off) ? s[t - off] : 0;
        __syncthreads();
        s[t] += v;
        __syncthreads();
    }
    if (t < nb) bsum[t] = s[t] - d;
}

__global__ void k_scan3(const int* __restrict__ deg, const int* __restrict__ bsum,
                        int* __restrict__ row_ptr, int* __restrict__ cursor) {
    int g = blockIdx.x * 256 + threadIdx.x;
    if (g < NN) {
        int v = row_ptr[g] + bsum[g >> 8];
        row_ptr[g] = v;
        cursor[g] = v;
        if (g == NN - 1) row_ptr[NN] = v + deg[g];
    }
}

// ---- scatter: 4 independent atomic->store chains per thread ----
__global__ void k_scatter(const int* __restrict__ row, const int* __restrict__ col,
                          int* __restrict__ cursor, int* __restrict__ col_sorted) {
    int base = blockIdx.x * 1024 + threadIdx.x;
    int e0 = base, e1 = base + 256, e2 = base + 512, e3 = base + 768;
    bool v0 = e0 < NE, v1 = e1 < NE, v2 = e2 < NE, v3 = e3 < NE;
    int p0, p1, p2, p3, c0 = 0, c1 = 0, c2 = 0, c3 = 0;
    if (v0) { c0 = col[e0]; p0 = atomicAdd(&cursor[row[e0]], 1); }
    if (v1) { c1 = col[e1]; p1 = atomicAdd(&cursor[row[e1]], 1); }
    if (v2) { c2 = col[e2]; p2 = atomicAdd(&cursor[row[e2]], 1); }
    if (v3) { c3 = col[e3]; p3 = atomicAdd(&cursor[row[e3]], 1); }
    if (v0) col_sorted[p0] = c0;
    if (v1) col_sorted[p1] = c1;
    if (v2) col_sorted[p2] = c2;
    if (v3) col_sorted[p3] = c3;
}

// ---- 64-wide SpMM on pre-scaled input: out[n] = -dinv[n]*sum_c ins[c]
//      has_sub: out = 2*out - sub; has_outs: outs = dinv[n]*out ----
__global__ __launch_bounds__(256) void k_spmm64(const float* __restrict__ ins, const float* __restrict__ sub,
                                                float* __restrict__ out, float* __restrict__ outs,
                                                const int* __restrict__ row_ptr, const int* __restrict__ cs,
                                                const float* __restrict__ dinv,
                                                int has_sub, int has_outs) {
    int n = blockIdx.x * 4 + (threadIdx.x >> 6);
    if (n >= NN) return;
    int nu = __builtin_amdgcn_readfirstlane(n);
    int lane = threadIdx.x & 63;
    int half = lane >> 5;
    int m = lane & 31;
    int s = row_ptr[nu], e = row_ptr[nu + 1];
    float ax0 = 0.f, ay0 = 0.f, ax1 = 0.f, ay1 = 0.f;
    float ax2 = 0.f, ay2 = 0.f, ax3 = 0.f, ay3 = 0.f;
    int i = s;
    // 8 edges per iteration: half-split (2) x unroll (4) -> 8 gathers in flight
    for (; i + 7 < e; i += 8) {
        int c0 = cs[i + half];
        int c1 = cs[i + 2 + half];
        int c2 = cs[i + 4 + half];
        int c3 = cs[i + 6 + half];
        float2 v0 = ((const float2*)(ins + (size_t)c0 * 64))[m];
        float2 v1 = ((const float2*)(ins + (size_t)c1 * 64))[m];
        float2 v2 = ((const float2*)(ins + (size_t)c2 * 64))[m];
        float2 v3 = ((const float2*)(ins + (size_t)c3 * 64))[m];
        ax0 += v0.x; ay0 += v0.y;
        ax1 += v1.x; ay1 += v1.y;
        ax2 += v2.x; ay2 += v2.y;
        ax3 += v3.x; ay3 += v3.y;
    }
    for (; i + 3 < e; i += 4) {
        int c0 = cs[i + half];
        int c1 = cs[i + 2 + half];
        float2 v0 = ((const float2*)(ins + (size_t)c0 * 64))[m];
        float2 v1 = ((const float2*)(ins + (size_t)c1 * 64))[m];
        ax0 += v0.x; ay0 += v0.y;
        ax1 += v1.x; ay1 += v1.y;
    }
    for (; i + 1 < e; i += 2) {
        int c = cs[i + half];
        float2 v = ((const float2*)(ins + (size_t)c * 64))[m];
        ax0 += v.x; ay0 += v.y;
    }
    if (i < e && half == 0) {
        int c = cs[i];
        float2 v = ((const float2*)(ins + (size_t)c * 64))[m];
        ax0 += v.x; ay0 += v.y;
    }
    float ax = (ax0 + ax1) + (ax2 + ax3);
    float ay = (ay0 + ay1) + (ay2 + ay3);
    ax += __shfl_xor(ax, 32);
    ay += __shfl_xor(ay, 32);
    if (half == 0) {
        float dn = dinv[nu];
        float rx = -dn * ax, ry = -dn * ay;
        if (has_sub) {
            float2 sv = ((const float2*)(sub + (size_t)nu * 64))[m];
            rx = 2.f * rx - sv.x;
            ry = 2.f * ry - sv.y;
        }
        float2 r; r.x = rx; r.y = ry;
        ((float2*)(out + (size_t)nu * 64))[m] = r;
        if (has_outs) {
            float2 rs; rs.x = dn * rx; rs.y = dn * ry;
            ((float2*)(outs + (size_t)nu * 64))[m] = rs;
        }
    }
}

// ---- dense layer 1: h = relu(x@W0 + t1@W1 + t2@W2 + b); wave = 8 nodes ----
__global__ __launch_bounds__(256) void k_dense1(const float* __restrict__ x, const float* __restrict__ t1,
                                                const float* __restrict__ t2, const float* __restrict__ W,
                                                const float* __restrict__ b, float* __restrict__ h) {
    __shared__ float Ws[3 * 64 * 64];
    for (int i = threadIdx.x; i < 3 * 64 * 64; i += 256) Ws[i] = W[i];
    __syncthreads();
    int lane = threadIdx.x & 63;
    int n0 = __builtin_amdgcn_readfirstlane((blockIdx.x * 4 + (threadIdx.x >> 6)) * 8);
    if (n0 >= NN) return;
    float bl = b[lane];
    float acc[8];
    #pragma unroll
    for (int j = 0; j < 8; ++j) acc[j] = bl;
    const float* arrs[3] = {x, t1, t2};
    #pragma unroll
    for (int s3 = 0; s3 < 3; ++s3) {
        const float* A = arrs[s3] + (size_t)n0 * 64;
        const float* Wp = Ws + s3 * 4096;
        #pragma unroll 4
        for (int i = 0; i < 64; ++i) {
            float w = Wp[i * 64 + lane];
            #pragma unroll
            for (int j = 0; j < 8; ++j) acc[j] += A[j * 64 + i] * w;
        }
    }
    #pragma unroll
    for (int j = 0; j < 8; ++j)
        h[(size_t)(n0 + j) * 64 + lane] = fmaxf(acc[j], 0.f);
}

// ---- layer-2 projection: Apre = h@(W2[0]-W2[2]) + b2;  Gs = dinv*[h@W2[1] | h@W2[2]]
//      out = Apre + P(g1) + 2*P(P(g2)) computed by the two narrow spmms below ----
__global__ __launch_bounds__(256) void k_proj(const float* __restrict__ h, const float* __restrict__ W2,
                                              const float* __restrict__ b2, const float* __restrict__ dinv,
                                              float* __restrict__ Apre, float* __restrict__ Gs) {
    __shared__ float Wall[64 * 48];
    for (int i = threadIdx.x; i < 64 * 48; i += 256) {
        int r = i / 48, c = i % 48;
        float w;
        if (c < 16)       w = W2[r * 16 + c] - W2[2048 + r * 16 + c];
        else if (c < 32)  w = W2[1024 + r * 16 + (c - 16)];
        else              w = W2[2048 + r * 16 + (c - 32)];
        Wall[i] = w;
    }
    __syncthreads();
    int lane = threadIdx.x & 63;
    int cl = lane < 48 ? lane : 0;
    int n0 = __builtin_amdgcn_readfirstlane((blockIdx.x * 4 + (threadIdx.x >> 6)) * 8);
    if (n0 >= NN) return;
    float acc[8];
    #pragma unroll
    for (int j = 0; j < 8; ++j) acc[j] = 0.f;
    const float* A = h + (size_t)n0 * 64;
    #pragma unroll 4
    for (int i = 0; i < 64; ++i) {
        float w = Wall[i * 48 + cl];
        #pragma unroll
        for (int j = 0; j < 8; ++j) acc[j] += A[j * 64 + i] * w;
    }
    #pragma unroll
    for (int j = 0; j < 8; ++j) {
        int n = n0 + j;
        if (lane < 16) Apre[(size_t)n * 16 + lane] = acc[j] + b2[lane];
        else if (lane < 48) Gs[(size_t)n * 32 + (lane - 16)] = acc[j] * dinv[n];
    }
}

// ---- 32-wide fused SpMM: q1 = P(g1); ts = dinv * P(g2) ----
__global__ __launch_bounds__(256) void k_spmm32(const float* __restrict__ Gs, float* __restrict__ q1,
                                                float* __restrict__ ts, const int* __restrict__ row_ptr,
                                                const int* __restrict__ cs, const float* __restrict__ dinv) {
    int n = blockIdx.x * 4 + (threadIdx.x >> 6);
    if (n >= NN) return;
    int nu = __builtin_amdgcn_readfirstlane(n);
    int lane = threadIdx.x & 63;
    int es = lane >> 5;      // 2 edges in parallel
    int f = lane & 31;
    int s = row_ptr[nu], e = row_ptr[nu + 1];
    float a0 = 0.f, a1 = 0.f;
    int i = s;
    for (; i + 3 < e; i += 4) {
        int c0 = cs[i + es];
        int c1 = cs[i + 2 + es];
        a0 += Gs[(size_t)c0 * 32 + f];
        a1 += Gs[(size_t)c1 * 32 + f];
    }
    for (; i + 1 < e; i += 2) {
        a0 += Gs[(size_t)cs[i + es] * 32 + f];
    }
    if (i < e && es == 0) a0 += Gs[(size_t)cs[i] * 32 + f];
    float a = a0 + a1;
    a += __shfl_xor(a, 32);
    if (es == 0) {
        float dn = dinv[nu];
        float v = -dn * a;
        if (f < 16) q1[(size_t)nu * 16 + f] = v;
        else        ts[(size_t)nu * 16 + (f - 16)] = dn * v;
    }
}

// ---- 16-wide SpMM + final combine + log_softmax ----
__global__ __launch_bounds__(256) void k_spmm16f(const float* __restrict__ ts, const float* __restrict__ Apre,
                                                 const float* __restrict__ q1, const int* __restrict__ row_ptr,
                                                 const int* __restrict__ cs, const float* __restrict__ dinv,
                                                 float* __restrict__ out) {
    int n = blockIdx.x * 4 + (threadIdx.x >> 6);
    if (n >= NN) return;
    int nu = __builtin_amdgcn_readfirstlane(n);
    int lane = threadIdx.x & 63;
    int es = lane >> 4;      // 4 edges in parallel
    int f = lane & 15;
    int s = row_ptr[nu], e = row_ptr[nu + 1];
    float a0 = 0.f, a1 = 0.f;
    int i = s;
    for (; i + 7 < e; i += 8) {
        int c0 = cs[i + es];
        int c1 = cs[i + 4 + es];
        a0 += ts[(size_t)c0 * 16 + f];
        a1 += ts[(size_t)c1 * 16 + f];
    }
    for (; i + 3 < e; i += 4) {
        a0 += ts[(size_t)cs[i + es] * 16 + f];
    }
    if (i + es < e) a0 += ts[(size_t)cs[i + es] * 16 + f];
    float a = a0 + a1;
    a += __shfl_xor(a, 16);
    a += __shfl_xor(a, 32);
    if (es == 0) {
        float dn = dinv[nu];
        float r = -dn * a;
        float o = Apre[(size_t)nu * 16 + f] + q1[(size_t)nu * 16 + f] + 2.f * r;
        float m = o;
        for (int off = 1; off < 16; off <<= 1) m = fmaxf(m, __shfl_xor(m, off, 16));
        float ex = expf(o - m);
        float ssum = ex;
        for (int off = 1; off < 16; off <<= 1) ssum += __shfl_xor(ssum, off, 16);
        out[(size_t)nu * 16 + f] = o - m - logf(ssum);
    }
}

extern "C" void kernel_launch(void* const* d_in, const int* in_sizes, int n_in,
                              void* d_out, int out_size, void* d_ws, size_t ws_size,
                              hipStream_t stream) {
    const float* x  = (const float*)d_in[0];
    const int*   ei = (const int*)d_in[1];
    const int*   row = ei;
    const int*   col = ei + NE;
    const float* W1 = (const float*)d_in[2];
    const float* b1 = (const float*)d_in[3];
    const float* W2 = (const float*)d_in[4];
    const float* b2 = (const float*)d_in[5];
    float* out = (float*)d_out;

    char* base = (char*)d_ws;
    size_t off = 0;
    auto alloc = [&](size_t bytes) -> char* {
        char* r = base + off;
        off = (off + bytes + 255) & ~(size_t)255;
        return r;
    };
    int*   deg        = (int*)alloc((size_t)NN * 4);
    float* dinv       = (float*)alloc((size_t)NN * 4);
    int*   row_ptr    = (int*)alloc((size_t)(NN + 1) * 4);
    int*   cursor     = (int*)alloc((size_t)NN * 4);
    int*   bsum       = (int*)alloc(512 * 4);
    int*   col_sorted = (int*)alloc((size_t)NE * 4);
    float* XS         = (float*)alloc((size_t)NN * 64 * 4);
    float* T1         = (float*)alloc((size_t)NN * 64 * 4);
    float* T1s        = (float*)alloc((size_t)NN * 64 * 4);
    float* T2         = (float*)alloc((size_t)NN * 64 * 4);
    float* H          = (float*)alloc((size_t)NN * 64 * 4);
    float* Apre       = (float*)alloc((size_t)NN * 16 * 4);
    float* Gs         = (float*)alloc((size_t)NN * 32 * 4);
    float* q1         = (float*)alloc((size_t)NN * 16 * 4);
    float* ts         = (float*)alloc((size_t)NN * 16 * 4);

    hipMemsetAsync(deg, 0, (size_t)NN * 4, stream);

    int nbN  = (NN + 255) / 256;
    int nbE4 = (NE + 1023) / 1024;
    k_deg<<<nbE4, 256, 0, stream>>>(row, deg);
    k_dinv<<<nbN, 256, 0, stream>>>(deg, dinv);
    k_scale<<<(NN * 16 + 255) / 256, 256, 0, stream>>>(x, dinv, XS);
    k_scan1<<<nbN, 256, 0, stream>>>(deg, row_ptr, bsum);
    k_scan2<<<1, 512, 0, stream>>>(bsum, nbN);
    k_scan3<<<nbN, 256, 0, stream>>>(deg, bsum, row_ptr, cursor);
    k_scatter<<<nbE4, 256, 0, stream>>>(row, col, cursor, col_sorted);

    int nbS = (NN + 3) / 4;   // wave per node
    // layer 1
    k_spmm64<<<nbS, 256, 0, stream>>>(XS, nullptr, T1, T1s, row_ptr, col_sorted, dinv, 0, 1);
    k_spmm64<<<nbS, 256, 0, stream>>>(T1s, x, T2, nullptr, row_ptr, col_sorted, dinv, 1, 0);
    k_dense1<<<3125, 256, 0, stream>>>(x, T1, T2, W1, b1, H);
    // layer 2: project to 16-wide first, then narrow propagations
    k_proj<<<3125, 256, 0, stream>>>(H, W2, b2, dinv, Apre, Gs);
    k_spmm32<<<nbS, 256, 0, stream>>>(Gs, q1, ts, row_ptr, col_sorted, dinv);
    k_spmm16f<<<nbS, 256, 0, stream>>>(ts, Apre, q1, row_ptr, col_sorted, dinv, out);
}